// Round 7
// baseline (547.735 us; speedup 1.0000x reference)
//
#include <hip/hip_runtime.h>
#include <hip/hip_bf16.h>
#include <stdint.h>

#define BB 4
#define SS 1024
#define DIM 2048
#define NH 16
#define QR 1024
#define KVR 512
#define NOPE 128
#define ROPE 64
#define VH 128
#define QKH 192
#define NTOK 4096

static constexpr float SCALE_ = 0.07216878364870322f; // 192^-0.5
static constexpr float EPS_ = 1e-6f;

typedef unsigned short u16;
typedef unsigned int u32;
using f32x4  = __attribute__((ext_vector_type(4))) float;
using bf16x8 = __attribute__((ext_vector_type(8))) __bf16;

#define MFMA16 __builtin_amdgcn_mfma_f32_16x16x32_bf16

__device__ __forceinline__ u16 f2b(float f) {
  u32 u = __float_as_uint(f);
  u32 r = u + 0x7fffu + ((u >> 16) & 1u);   // RNE
  return (u16)(r >> 16);
}
__device__ __forceinline__ u32 pk2(float a, float b) {
  return (u32)f2b(a) | ((u32)f2b(b) << 16);
}
__device__ __forceinline__ float b2f(u32 hi16) {
  return __uint_as_float(hi16 << 16);
}

// ---------------- f32 -> bf16 convert (8 elems/thread) ----------------
__global__ __launch_bounds__(256) void cvt_bf16(const float* __restrict__ in,
                                                u16* __restrict__ out, int n) {
  int i = (blockIdx.x * 256 + threadIdx.x) * 8;
  if (i >= n) return;
  float4 a = *(const float4*)&in[i];
  float4 b = *(const float4*)&in[i + 4];
  uint4 o;
  o.x = pk2(a.x, a.y); o.y = pk2(a.z, a.w);
  o.z = pk2(b.x, b.y); o.w = pk2(b.z, b.w);
  *(uint4*)&out[i] = o;
}

// ---------------- wkv_b split: wb_k transposed per head, wb_v straight ----------------
__global__ __launch_bounds__(256) void prep_wkvb(const float* __restrict__ w,
                                                 u16* __restrict__ wbkt,
                                                 u16* __restrict__ wbv) {
  int idx = blockIdx.x * 256 + threadIdx.x;   // over 16*256*512
  int c = idx & 511;
  int rowh = idx >> 9;
  int h = rowh >> 8;
  int dr = rowh & 255;
  float v = w[idx];
  if (dr < NOPE) wbkt[((h * KVR + c) << 7) + dr] = f2b(v);           // (NH,512,128)
  else           wbv[((h * VH + (dr - NOPE)) << 9) + c] = f2b(v);    // (NH,128,512)
}

// ---------------- RMSNorm over 1024 (q path) ----------------
__global__ __launch_bounds__(256) void rms_q_kernel(const float* __restrict__ X,
                                                    const float* __restrict__ w,
                                                    u16* __restrict__ out) {
  int r = blockIdx.x, tid = threadIdx.x;
  const float4 v = *(const float4*)&X[(long)r * QR + tid * 4];
  float ss = v.x * v.x + v.y * v.y + v.z * v.z + v.w * v.w;
  for (int m = 1; m < 64; m <<= 1) ss += __shfl_xor(ss, m);
  __shared__ float red[4];
  if ((tid & 63) == 0) red[tid >> 6] = ss;
  __syncthreads();
  float tot = red[0] + red[1] + red[2] + red[3];
  float sc = rsqrtf(tot / QR + EPS_);
  float4 wv = *(const float4*)&w[tid * 4];
  uint2 o;
  o.x = pk2(v.x * sc * wv.x, v.y * sc * wv.y);
  o.y = pk2(v.z * sc * wv.z, v.w * sc * wv.w);
  *(uint2*)&out[(long)r * QR + tid * 4] = o;
}

// ---------------- q post (bf16 input): split nope / rope(pe)*SCALE, head-major ----------------
__global__ __launch_bounds__(256) void post_q_kernel(const u16* __restrict__ C2,
                                                     const float* __restrict__ fc,
                                                     const float* __restrict__ fs,
                                                     u16* __restrict__ qn,
                                                     u16* __restrict__ qp) {
  int r = blockIdx.x, tid = threadIdx.x;
  int s = r & (SS - 1);
  const u16* row = C2 + (long)r * (NH * QKH);
  for (int j = tid; j < NH * QKH / 2; j += 256) {
    int col = j * 2;
    int h = col / QKH;
    int dd = col - h * QKH;
    u32 pair = *(const u32*)&row[col];
    if (dd < NOPE) {
      *(u32*)&qn[((long)h * NTOK + r) * NOPE + dd] = pair;   // already bf16
    } else {
      float x0 = b2f(pair & 0xffffu), x1 = b2f(pair >> 16);
      int jr = (dd - NOPE) >> 1;
      float c = fc[s * 32 + jr], sn = fs[s * 32 + jr];
      *(u32*)&qp[((long)h * NTOK + r) * ROPE + (dd - NOPE)] =
          pk2((x0 * c - x1 * sn) * SCALE_, (x0 * sn + x1 * c) * SCALE_);
    }
  }
}

// ---------------- kv post: rmsnorm(512) -> kv_sw (XOR-swizzled) + kv^T, rope k_pe_sw ----------------
// Swizzle: element index d' = d ^ ((t&7)<<3) within each row.
__global__ __launch_bounds__(256) void post_kv_kernel(const float* __restrict__ C3,
                                                      const float* __restrict__ w,
                                                      const float* __restrict__ fc,
                                                      const float* __restrict__ fs,
                                                      u16* __restrict__ kv_sw,
                                                      u16* __restrict__ kvt,
                                                      u16* __restrict__ kpe_sw) {
  int r = blockIdx.x, tid = threadIdx.x;
  int b = r >> 10, t = r & (SS - 1);
  const float* row = C3 + (long)r * 576;
  float2 v = *(const float2*)&row[tid * 2];
  float ss = v.x * v.x + v.y * v.y;
  for (int m = 1; m < 64; m <<= 1) ss += __shfl_xor(ss, m);
  __shared__ float red[4];
  if ((tid & 63) == 0) red[tid >> 6] = ss;
  __syncthreads();
  float tot = red[0] + red[1] + red[2] + red[3];
  float sc = rsqrtf(tot / KVR + EPS_);
  int c = tid * 2;
  int xm = (t & 7) << 3;
  float y0 = v.x * sc * w[c], y1 = v.y * sc * w[c + 1];
  *(u32*)&kv_sw[((long)b * SS + t) * KVR + (c ^ xm)] = pk2(y0, y1);
  kvt[((long)b * KVR + c) * SS + t] = f2b(y0);
  kvt[((long)b * KVR + c + 1) * SS + t] = f2b(y1);
  if (tid < 32) {
    float x0 = row[KVR + tid * 2], x1 = row[KVR + tid * 2 + 1];
    float cc = fc[t * 32 + tid], sn = fs[t * 32 + tid];
    *(u32*)&kpe_sw[((long)b * SS + t) * ROPE + ((tid * 2) ^ xm)] =
        pk2(x0 * cc - x1 * sn, x0 * sn + x1 * cc);
  }
}

// ---------------- GEMM: C(M,N) = A(M,K) * B(N,K)^T, bf16 in, f32/bf16 out ----------------
template <bool CBF16>
__global__ __launch_bounds__(256) void gemm_bt(const u16* __restrict__ Ag,
                                               const u16* __restrict__ Bg,
                                               void* __restrict__ Cg,
                                               int M, int N, int K,
                                               int lda, int ldb, int ldc,
                                               long sA, long sB, long sC,
                                               float oscale) {
  const u16* A = Ag + (long)blockIdx.z * sA;
  const u16* Bm = Bg + (long)blockIdx.z * sB;
  const int row0 = blockIdx.y * 128;
  const int col0 = blockIdx.x * 128;
  const int tid = threadIdx.x;
  const int wave = tid >> 6, lane = tid & 63;
  const int g = lane >> 4, r = lane & 15;
  const int wr = wave >> 1, wc = wave & 1;

  __shared__ u16 As[2][128 * 32];
  __shared__ u16 Bs[2][128 * 32];

  f32x4 acc[4][4] = {};
  const int nk = K >> 5;

  auto stage = [&](int kt, int p) {
    int k0 = kt << 5;
#pragma unroll
    for (int j = 0; j < 2; ++j) {
      int ldsoff = (j * 4096 + wave * 1024) >> 1;
      int rowi = j * 64 + wave * 16 + (lane >> 2);
      int coli = (lane & 3) << 3;
      const u16* ga = A + (long)(row0 + rowi) * lda + k0 + coli;
      __builtin_amdgcn_global_load_lds(
          (const __attribute__((address_space(1))) void*)ga,
          (__attribute__((address_space(3))) void*)(&As[p][ldsoff]), 16, 0, 0);
      int rb = col0 + rowi; if (rb > N - 1) rb = N - 1;
      const u16* gb = Bm + (long)rb * ldb + k0 + coli;
      __builtin_amdgcn_global_load_lds(
          (const __attribute__((address_space(1))) void*)gb,
          (__attribute__((address_space(3))) void*)(&Bs[p][ldsoff]), 16, 0, 0);
    }
  };

  stage(0, 0);
  for (int kt = 0; kt < nk; ++kt) {
    __syncthreads();
    if (kt + 1 < nk) stage(kt + 1, (kt + 1) & 1);
    const int p = kt & 1;
    bf16x8 af[4], bf[4];
#pragma unroll
    for (int i = 0; i < 4; i++) {
      af[i] = *(const bf16x8*)&As[p][(wr * 64 + i * 16 + r) * 32 + g * 8];
      bf[i] = *(const bf16x8*)&Bs[p][(wc * 64 + i * 16 + r) * 32 + g * 8];
    }
#pragma unroll
    for (int i = 0; i < 4; i++)
#pragma unroll
      for (int j = 0; j < 4; j++)
        acc[i][j] = MFMA16(af[i], bf[j], acc[i][j], 0, 0, 0);
  }

#pragma unroll
  for (int i = 0; i < 4; i++)
#pragma unroll
    for (int j = 0; j < 4; j++) {
      int rowb = row0 + wr * 64 + i * 16 + g * 4;
      int colc = col0 + wc * 64 + j * 16 + r;
      if (colc < N) {
        if constexpr (CBF16) {
          u16* C = (u16*)Cg + (long)blockIdx.z * sC;
#pragma unroll
          for (int e = 0; e < 4; e++)
            C[(long)(rowb + e) * ldc + colc] = f2b(acc[i][j][e] * oscale);
        } else {
          float* C = (float*)Cg + (long)blockIdx.z * sC;
#pragma unroll
          for (int e = 0; e < 4; e++)
            C[(long)(rowb + e) * ldc + colc] = acc[i][j][e] * oscale;
        }
      }
    }
}

// ---------------- flash attention v7: occupancy-first ----------------
// 512 blocks (4b x 16h x 8 chunks), one 128-row chunk each, KVBLK=32,
// LDS 47KB -> 3 blocks/CU resident; cross-block TLP hides barriers/latency.
// 8 waves: QK per-wave 16 rows (qf[18] regs incl. rope), K+Kpe staged in LDS;
// PV all-rows x own 64 V-cols; 2 barriers per 32-key tile.
__global__ __launch_bounds__(512) void attn_kernel(
    const u16* __restrict__ q_lat, const u16* __restrict__ q_pe,
    const u16* __restrict__ kv_sw, const u16* __restrict__ kvt,
    const u16* __restrict__ kpe_sw, u16* __restrict__ o_lat) {
  const int bid = blockIdx.x;
  const int xcd = bid & 7;                 // dispatch round-robins XCDs
  const int b = xcd >> 1;                  // batch pinned to XCD pair
  const int idx = bid >> 3;                // 0..63
  const int h = idx & 15;
  const int hi = idx >> 4;                 // 0..3
  const int jc = ((xcd & 1) ? 3 : 7) - hi; // big chunks first in launch order
  const int qa = jc * 128;
  const int nt = 4 * jc + 4;               // 32-key tiles

  const int wv = threadIdx.x >> 6, lane = threadIdx.x & 63;
  const int g = lane >> 4, r = lane & 15;
  const int xm = (r & 7) << 3;

  __shared__ __attribute__((aligned(16))) u16 Ks[32 * 512];   // 32 KB swizzled K
  __shared__ __attribute__((aligned(16))) u16 Kp[32 * 64];    // 4 KB swizzled Kpe
  __shared__ __attribute__((aligned(16))) u16 P[128][40];     // 10 KB padded
  __shared__ float alphab[128];
  __shared__ float lbuf[128];

  const u16* KVg = kv_sw + (long)b * SS * KVR;
  const u16* KPg = kpe_sw + (long)b * SS * ROPE;
  const u16* KT  = kvt + (long)b * KVR * SS;

  auto stage = [&](int t0) {
#pragma unroll
    for (int i = 0; i < 4; ++i) {
      int row = wv * 4 + i;
      const u16* ga = KVg + (long)(t0 + row) * KVR + lane * 8;
      __builtin_amdgcn_global_load_lds(
          (const __attribute__((address_space(1))) void*)ga,
          (__attribute__((address_space(3))) void*)(&Ks[row * 512]), 16, 0, 0);
    }
    if (wv < 4) {   // 4 instrs cover 32 rows x 64 (rows contiguous)
      const u16* ga = KPg + (long)(t0 + wv * 8) * ROPE + lane * 8;
      __builtin_amdgcn_global_load_lds(
          (const __attribute__((address_space(1))) void*)ga,
          (__attribute__((address_space(3))) void*)(&Kp[wv * 8 * 64]), 16, 0, 0);
    }
  };

  const int q_row = qa + wv * 16 + r;
  const u16* Q  = q_lat + ((long)h * NTOK + (long)b * SS + q_row) * KVR;
  const u16* Qp = q_pe  + ((long)h * NTOK + (long)b * SS + q_row) * ROPE;
  bf16x8 qf[18];
#pragma unroll
  for (int c = 0; c < 16; ++c) qf[c] = *(const bf16x8*)&Q[c * 32 + g * 8];
  qf[16] = *(const bf16x8*)&Qp[g * 8];
  qf[17] = *(const bf16x8*)&Qp[32 + g * 8];

  f32x4 acc[8][4];
#pragma unroll
  for (int i = 0; i < 8; i++)
#pragma unroll
    for (int jn = 0; jn < 4; jn++) acc[i][jn] = f32x4{0.f, 0.f, 0.f, 0.f};
  float m_run = -1e30f, l_run = 0.f;

  stage(0);
  __syncthreads();

  for (int tt = 0; tt < nt; ++tt) {
    const int t0 = tt << 5;

    // QK^T over 32 keys (2 row-groups of 16), uniform 18 c-steps
    f32x4 st0 = {0.f, 0.f, 0.f, 0.f}, st1 = {0.f, 0.f, 0.f, 0.f};
#pragma unroll
    for (int c = 0; c < 16; ++c) {
      int ix = (c * 32 + g * 8) ^ xm;
      bf16x8 k0 = *(const bf16x8*)&Ks[r * 512 + ix];
      bf16x8 k1 = *(const bf16x8*)&Ks[(16 + r) * 512 + ix];
      st0 = MFMA16(k0, qf[c], st0, 0, 0, 0);
      st1 = MFMA16(k1, qf[c], st1, 0, 0, 0);
    }
#pragma unroll
    for (int c = 0; c < 2; ++c) {
      int ix = (c * 32 + g * 8) ^ xm;
      bf16x8 k0 = *(const bf16x8*)&Kp[r * 64 + ix];
      bf16x8 k1 = *(const bf16x8*)&Kp[(16 + r) * 64 + ix];
      st0 = MFMA16(k0, qf[16 + c], st0, 0, 0, 0);
      st1 = MFMA16(k1, qf[16 + c], st1, 0, 0, 0);
    }

    // softmax (lane owns q_row; keys {t0+g*4+i, t0+16+g*4+i})
    float sv[8];
    float smax = -1e30f;
#pragma unroll
    for (int i = 0; i < 4; i++) {
      int t = t0 + g * 4 + i;
      sv[i]     = (t      <= q_row) ? st0[i] : -1e30f;
      sv[4 + i] = (t + 16 <= q_row) ? st1[i] : -1e30f;
      smax = fmaxf(smax, fmaxf(sv[i], sv[4 + i]));
    }
    smax = fmaxf(smax, __shfl_xor(smax, 16));
    smax = fmaxf(smax, __shfl_xor(smax, 32));
    float m_new = fmaxf(m_run, smax);
    float alpha = __expf(m_run - m_new);
    float p[8], ps = 0.f;
#pragma unroll
    for (int i = 0; i < 8; i++) {
      p[i] = (sv[i] < -1e29f) ? 0.f : __expf(sv[i] - m_new);
      ps += p[i];
    }
    ps += __shfl_xor(ps, 16);
    ps += __shfl_xor(ps, 32);
    l_run = l_run * alpha + ps;
    m_run = m_new;

    uint2 pw0, pw1;
    pw0.x = pk2(p[0], p[1]); pw0.y = pk2(p[2], p[3]);
    pw1.x = pk2(p[4], p[5]); pw1.y = pk2(p[6], p[7]);
    *(uint2*)&P[wv * 16 + r][g * 4]      = pw0;
    *(uint2*)&P[wv * 16 + r][16 + g * 4] = pw1;
    if (g == 0) alphab[wv * 16 + r] = alpha;
    __syncthreads();                     // B1: P/alpha visible; Ks reads retired
    if (tt + 1 < nt) stage(t0 + 32);     // overwrite Ks/Kp; drained at B2

    // PV: all 128 rows x own 64 cols
    bf16x8 vf[4];
#pragma unroll
    for (int nc = 0; nc < 4; ++nc)
      vf[nc] = *(const bf16x8*)&KT[(long)(wv * 64 + nc * 16 + r) * SS + t0 + g * 8];
#pragma unroll
    for (int mc = 0; mc < 8; ++mc) {
      bf16x8 pa = *(const bf16x8*)&P[mc * 16 + r][g * 8];
      f32x4 a4 = *(const f32x4*)&alphab[mc * 16 + g * 4];
#pragma unroll
      for (int nc = 0; nc < 4; ++nc) {
        f32x4 t = acc[mc][nc] * a4;
        acc[mc][nc] = MFMA16(pa, vf[nc], t, 0, 0, 0);
      }
    }
    __syncthreads();                     // B2: stage drained; P safe to rewrite
  }

  if (g == 0) lbuf[wv * 16 + r] = l_run;
  __syncthreads();
  u16* O = o_lat + ((long)h * NTOK + (long)b * SS + qa) * KVR;
#pragma unroll
  for (int mc = 0; mc < 8; ++mc) {
    f32x4 li = *(const f32x4*)&lbuf[mc * 16 + g * 4];
#pragma unroll
    for (int e = 0; e < 4; e++) li[e] = 1.f / li[e];
#pragma unroll
    for (int nc = 0; nc < 4; ++nc) {
      int col = wv * 64 + nc * 16 + r;
#pragma unroll
      for (int e = 0; e < 4; e++)
        O[(long)(mc * 16 + g * 4 + e) * KVR + col] = f2b(acc[mc][nc][e] * li[e]);
    }
  }
}

// ---------------- host launch ----------------
extern "C" void kernel_launch(void* const* d_in, const int* in_sizes, int n_in,
                              void* d_out, int out_size, void* d_ws, size_t ws_size,
                              hipStream_t stream) {
  (void)in_sizes; (void)n_in; (void)out_size; (void)ws_size;
  const float* x    = (const float*)d_in[0];
  const float* fc   = (const float*)d_in[2];
  const float* fs   = (const float*)d_in[3];
  const float* wqa  = (const float*)d_in[4];
  const float* qnw  = (const float*)d_in[5];
  const float* wqb  = (const float*)d_in[6];
  const float* wkva = (const float*)d_in[7];
  const float* kvnw = (const float*)d_in[8];
  const float* wkvb = (const float*)d_in[9];
  const float* wo   = (const float*)d_in[10];
  float* out = (float*)d_out;

  char* w = (char*)d_ws;
  size_t off = 0;
  auto alloc = [&](size_t bytes) {
    void* p = w + off;
    off += (bytes + 255) & ~(size_t)255;
    return p;
  };
  // ---- persistent region ----
  u16* wbkt   = (u16*)alloc((size_t)NH * KVR * NOPE * 2);
  u16* wbv    = (u16*)alloc((size_t)NH * VH * KVR * 2);
  u16* wo_b   = (u16*)alloc((size_t)DIM * DIM * 2);
  u16* qnope  = (u16*)alloc((size_t)NH * NTOK * NOPE * 2);
  u16* qpe    = (u16*)alloc((size_t)NH * NTOK * ROPE * 2);
  u16* kv_sw  = (u16*)alloc((size_t)BB * SS * KVR * 2);
  u16* kvt    = (u16*)alloc((size_t)BB * KVR * SS * 2);
  u16* kpe_sw = (u16*)alloc((size_t)BB * SS * ROPE * 2);
  u16* oflat  = (u16*)alloc((size_t)NTOK * DIM * 2);
  // ---- transient region, later overlaid by qlat/olat ----
  u16* qlat   = (u16*)(w + off);            // overlay base
  u16* olat   = qlat;                       // attention writes O in-place over Q
  u16* x_bf   = (u16*)alloc((size_t)NTOK * DIM * 2);
  u16* wqa_b  = (u16*)alloc((size_t)QR * DIM * 2);
  u16* wqb_b  = (u16*)alloc((size_t)NH * QKH * QR * 2);
  u16* wkva_b = (u16*)alloc((size_t)576 * DIM * 2);
  u16* qn     = (u16*)alloc((size_t)NTOK * QR * 2);
  float* C1   = (float*)alloc((size_t)NTOK * QR * 4);
  u16* C2b    = (u16*)alloc((size_t)NTOK * NH * QKH * 2);

  cvt_bf16<<<(NTOK * DIM) / 2048, 256, 0, stream>>>(x, x_bf, NTOK * DIM);
  cvt_bf16<<<(QR * DIM) / 2048, 256, 0, stream>>>(wqa, wqa_b, QR * DIM);
  cvt_bf16<<<(NH * QKH * QR) / 2048, 256, 0, stream>>>(wqb, wqb_b, NH * QKH * QR);
  cvt_bf16<<<(576 * DIM) / 2048, 256, 0, stream>>>(wkva, wkva_b, 576 * DIM);
  cvt_bf16<<<(DIM * DIM) / 2048, 256, 0, stream>>>(wo, wo_b, DIM * DIM);
  prep_wkvb<<<(NH * 256 * KVR) / 256, 256, 0, stream>>>(wkvb, wbkt, wbv);

  gemm_bt<false><<<dim3(QR / 128, NTOK / 128, 1), 256, 0, stream>>>(
      x_bf, wqa_b, C1, NTOK, QR, DIM, DIM, DIM, QR, 0, 0, 0, 1.f);
  rms_q_kernel<<<NTOK, 256, 0, stream>>>(C1, qnw, qn);
  gemm_bt<true><<<dim3(NH * QKH / 128, NTOK / 128, 1), 256, 0, stream>>>(
      qn, wqb_b, C2b, NTOK, NH * QKH, QR, QR, QR, NH * QKH, 0, 0, 0, 1.f);
  post_q_kernel<<<NTOK, 256, 0, stream>>>(C2b, fc, fs, qnope, qpe);
  gemm_bt<false><<<dim3(5, NTOK / 128, 1), 256, 0, stream>>>(
      x_bf, wkva_b, C1, NTOK, 576, DIM, DIM, DIM, 576, 0, 0, 0, 1.f);
  post_kv_kernel<<<NTOK, 256, 0, stream>>>(C1, kvnw, fc, fs, kv_sw, kvt, kpe_sw);
  // q_lat pre-scaled by SCALE_ (softmax scale folded into Q)
  gemm_bt<true><<<dim3(KVR / 128, NTOK / 128, NH), 256, 0, stream>>>(
      qnope, wbkt, qlat, NTOK, KVR, NOPE, NOPE, NOPE, KVR,
      (long)NTOK * NOPE, (long)KVR * NOPE, (long)NTOK * KVR, SCALE_);
  attn_kernel<<<dim3(512, 1, 1), 512, 0, stream>>>(
      qlat, qpe, kv_sw, kvt, kpe_sw, olat);
  gemm_bt<true><<<dim3(1, NTOK / 128, NH), 256, 0, stream>>>(
      olat, wbv, oflat, NTOK, VH, KVR, KVR, KVR, DIM,
      (long)NTOK * KVR, (long)VH * KVR, (long)VH, 1.f);
  gemm_bt<false><<<dim3(DIM / 128, NTOK / 128, 1), 256, 0, stream>>>(
      oflat, wo_b, out, NTOK, DIM, DIM, DIM, DIM, DIM, 0, 0, 0, 1.f);
}

// Round 8
// 494.145 us; speedup vs baseline: 1.1084x; 1.1084x over previous
//
#include <hip/hip_runtime.h>
#include <hip/hip_bf16.h>
#include <stdint.h>

#define BB 4
#define SS 1024
#define DIM 2048
#define NH 16
#define QR 1024
#define KVR 512
#define NOPE 128
#define ROPE 64
#define VH 128
#define QKH 192
#define NTOK 4096

static constexpr float SCALE_ = 0.07216878364870322f; // 192^-0.5
static constexpr float EPS_ = 1e-6f;

typedef unsigned short u16;
typedef unsigned int u32;
using f32x4  = __attribute__((ext_vector_type(4))) float;
using bf16x8 = __attribute__((ext_vector_type(8))) __bf16;

#define MFMA16 __builtin_amdgcn_mfma_f32_16x16x32_bf16

__device__ __forceinline__ u16 f2b(float f) {
  u32 u = __float_as_uint(f);
  u32 r = u + 0x7fffu + ((u >> 16) & 1u);   // RNE
  return (u16)(r >> 16);
}
__device__ __forceinline__ u32 pk2(float a, float b) {
  return (u32)f2b(a) | ((u32)f2b(b) << 16);
}
__device__ __forceinline__ float b2f(u32 hi16) {
  return __uint_as_float(hi16 << 16);
}
__device__ __forceinline__ void gll16(const u16* g, u16* l) {
  __builtin_amdgcn_global_load_lds(
      (const __attribute__((address_space(1))) void*)g,
      (__attribute__((address_space(3))) void*)l, 16, 0, 0);
}

// ---------------- f32 -> bf16 convert (8 elems/thread) ----------------
__global__ __launch_bounds__(256) void cvt_bf16(const float* __restrict__ in,
                                                u16* __restrict__ out, int n) {
  int i = (blockIdx.x * 256 + threadIdx.x) * 8;
  if (i >= n) return;
  float4 a = *(const float4*)&in[i];
  float4 b = *(const float4*)&in[i + 4];
  uint4 o;
  o.x = pk2(a.x, a.y); o.y = pk2(a.z, a.w);
  o.z = pk2(b.x, b.y); o.w = pk2(b.z, b.w);
  *(uint4*)&out[i] = o;
}

// ---------------- wkv_b split: wb_k transposed per head, wb_v straight ----------------
__global__ __launch_bounds__(256) void prep_wkvb(const float* __restrict__ w,
                                                 u16* __restrict__ wbkt,
                                                 u16* __restrict__ wbv) {
  int idx = blockIdx.x * 256 + threadIdx.x;   // over 16*256*512
  int c = idx & 511;
  int rowh = idx >> 9;
  int h = rowh >> 8;
  int dr = rowh & 255;
  float v = w[idx];
  if (dr < NOPE) wbkt[((h * KVR + c) << 7) + dr] = f2b(v);           // (NH,512,128)
  else           wbv[((h * VH + (dr - NOPE)) << 9) + c] = f2b(v);    // (NH,128,512)
}

// ---------------- RMSNorm over 1024 (q path) ----------------
__global__ __launch_bounds__(256) void rms_q_kernel(const float* __restrict__ X,
                                                    const float* __restrict__ w,
                                                    u16* __restrict__ out) {
  int r = blockIdx.x, tid = threadIdx.x;
  const float4 v = *(const float4*)&X[(long)r * QR + tid * 4];
  float ss = v.x * v.x + v.y * v.y + v.z * v.z + v.w * v.w;
  for (int m = 1; m < 64; m <<= 1) ss += __shfl_xor(ss, m);
  __shared__ float red[4];
  if ((tid & 63) == 0) red[tid >> 6] = ss;
  __syncthreads();
  float tot = red[0] + red[1] + red[2] + red[3];
  float sc = rsqrtf(tot / QR + EPS_);
  float4 wv = *(const float4*)&w[tid * 4];
  uint2 o;
  o.x = pk2(v.x * sc * wv.x, v.y * sc * wv.y);
  o.y = pk2(v.z * sc * wv.z, v.w * sc * wv.w);
  *(uint2*)&out[(long)r * QR + tid * 4] = o;
}

// ---------------- q post (bf16 input): split nope / rope(pe)*SCALE, head-major ----------------
__global__ __launch_bounds__(256) void post_q_kernel(const u16* __restrict__ C2,
                                                     const float* __restrict__ fc,
                                                     const float* __restrict__ fs,
                                                     u16* __restrict__ qn,
                                                     u16* __restrict__ qp) {
  int r = blockIdx.x, tid = threadIdx.x;
  int s = r & (SS - 1);
  const u16* row = C2 + (long)r * (NH * QKH);
  for (int j = tid; j < NH * QKH / 2; j += 256) {
    int col = j * 2;
    int h = col / QKH;
    int dd = col - h * QKH;
    u32 pair = *(const u32*)&row[col];
    if (dd < NOPE) {
      *(u32*)&qn[((long)h * NTOK + r) * NOPE + dd] = pair;   // already bf16
    } else {
      float x0 = b2f(pair & 0xffffu), x1 = b2f(pair >> 16);
      int jr = (dd - NOPE) >> 1;
      float c = fc[s * 32 + jr], sn = fs[s * 32 + jr];
      *(u32*)&qp[((long)h * NTOK + r) * ROPE + (dd - NOPE)] =
          pk2((x0 * c - x1 * sn) * SCALE_, (x0 * sn + x1 * c) * SCALE_);
    }
  }
}

// ---------------- kv post: rmsnorm(512) -> kv_sw (XOR-swizzled) + v8 (k-subtiled), rope k_pe_sw ----
// kv_sw: element d' = d ^ ((t&7)<<3) within each row (QK LDS-read swizzle).
// v8: element (t,c) -> ((t>>3)*512 + c)*8 + (t&7)  => 32-key V tile contiguous,
//     PV B-fragment = one bf16x8 LDS read (8 consecutive k's per col).
__global__ __launch_bounds__(256) void post_kv_kernel(const float* __restrict__ C3,
                                                      const float* __restrict__ w,
                                                      const float* __restrict__ fc,
                                                      const float* __restrict__ fs,
                                                      u16* __restrict__ kv_sw,
                                                      u16* __restrict__ v8,
                                                      u16* __restrict__ kpe_sw) {
  int r = blockIdx.x, tid = threadIdx.x;
  int b = r >> 10, t = r & (SS - 1);
  const float* row = C3 + (long)r * 576;
  float2 v = *(const float2*)&row[tid * 2];
  float ss = v.x * v.x + v.y * v.y;
  for (int m = 1; m < 64; m <<= 1) ss += __shfl_xor(ss, m);
  __shared__ float red[4];
  if ((tid & 63) == 0) red[tid >> 6] = ss;
  __syncthreads();
  float tot = red[0] + red[1] + red[2] + red[3];
  float sc = rsqrtf(tot / KVR + EPS_);
  int c = tid * 2;
  int xm = (t & 7) << 3;
  float y0 = v.x * sc * w[c], y1 = v.y * sc * w[c + 1];
  *(u32*)&kv_sw[((long)b * SS + t) * KVR + (c ^ xm)] = pk2(y0, y1);
  long o8 = (long)b * SS * KVR + ((long)(t >> 3) * 512 + c) * 8 + (t & 7);
  v8[o8]     = f2b(y0);
  v8[o8 + 8] = f2b(y1);
  if (tid < 32) {
    float x0 = row[KVR + tid * 2], x1 = row[KVR + tid * 2 + 1];
    float cc = fc[t * 32 + tid], sn = fs[t * 32 + tid];
    *(u32*)&kpe_sw[((long)b * SS + t) * ROPE + ((tid * 2) ^ xm)] =
        pk2(x0 * cc - x1 * sn, x0 * sn + x1 * cc);
  }
}

// ---------------- GEMM: C(M,N) = A(M,K) * B(N,K)^T, bf16 in, f32/bf16 out ----------------
template <bool CBF16>
__global__ __launch_bounds__(256) void gemm_bt(const u16* __restrict__ Ag,
                                               const u16* __restrict__ Bg,
                                               void* __restrict__ Cg,
                                               int M, int N, int K,
                                               int lda, int ldb, int ldc,
                                               long sA, long sB, long sC,
                                               float oscale) {
  const u16* A = Ag + (long)blockIdx.z * sA;
  const u16* Bm = Bg + (long)blockIdx.z * sB;
  const int row0 = blockIdx.y * 128;
  const int col0 = blockIdx.x * 128;
  const int tid = threadIdx.x;
  const int wave = tid >> 6, lane = tid & 63;
  const int g = lane >> 4, r = lane & 15;
  const int wr = wave >> 1, wc = wave & 1;

  __shared__ u16 As[2][128 * 32];
  __shared__ u16 Bs[2][128 * 32];

  f32x4 acc[4][4] = {};
  const int nk = K >> 5;

  auto stage = [&](int kt, int p) {
    int k0 = kt << 5;
#pragma unroll
    for (int j = 0; j < 2; ++j) {
      int ldsoff = (j * 4096 + wave * 1024) >> 1;
      int rowi = j * 64 + wave * 16 + (lane >> 2);
      int coli = (lane & 3) << 3;
      const u16* ga = A + (long)(row0 + rowi) * lda + k0 + coli;
      gll16(ga, &As[p][ldsoff]);
      int rb = col0 + rowi; if (rb > N - 1) rb = N - 1;
      const u16* gb = Bm + (long)rb * ldb + k0 + coli;
      gll16(gb, &Bs[p][ldsoff]);
    }
  };

  stage(0, 0);
  for (int kt = 0; kt < nk; ++kt) {
    __syncthreads();
    if (kt + 1 < nk) stage(kt + 1, (kt + 1) & 1);
    const int p = kt & 1;
    bf16x8 af[4], bf[4];
#pragma unroll
    for (int i = 0; i < 4; i++) {
      af[i] = *(const bf16x8*)&As[p][(wr * 64 + i * 16 + r) * 32 + g * 8];
      bf[i] = *(const bf16x8*)&Bs[p][(wc * 64 + i * 16 + r) * 32 + g * 8];
    }
#pragma unroll
    for (int i = 0; i < 4; i++)
#pragma unroll
      for (int j = 0; j < 4; j++)
        acc[i][j] = MFMA16(af[i], bf[j], acc[i][j], 0, 0, 0);
  }

#pragma unroll
  for (int i = 0; i < 4; i++)
#pragma unroll
    for (int j = 0; j < 4; j++) {
      int rowb = row0 + wr * 64 + i * 16 + g * 4;
      int colc = col0 + wc * 64 + j * 16 + r;
      if (colc < N) {
        if constexpr (CBF16) {
          u16* C = (u16*)Cg + (long)blockIdx.z * sC;
#pragma unroll
          for (int e = 0; e < 4; e++)
            C[(long)(rowb + e) * ldc + colc] = f2b(acc[i][j][e] * oscale);
        } else {
          float* C = (float*)Cg + (long)blockIdx.z * sC;
#pragma unroll
          for (int e = 0; e < 4; e++)
            C[(long)(rowb + e) * ldc + colc] = acc[i][j][e] * oscale;
        }
      }
    }
}

// ---------------- flash attention v8 ----------------
// 256 blocks (perfectly balanced 36 tiles: seg pair jp,7-jp), batch pinned to
// XCD pair. 8 waves; QK per-wave 16 rows (qf[18] in regs); K,V,kpe all staged
// to LDS (dbuf) at tile TOP -> drain hidden under QK; PV V-fragments are single
// ds_read_b128 from subtiled Vs (no global gathers in the loop).
__global__ __launch_bounds__(512) void attn_kernel(
    const u16* __restrict__ q_lat, const u16* __restrict__ q_pe,
    const u16* __restrict__ kv_sw, const u16* __restrict__ v8g,
    const u16* __restrict__ kpe_sw, u16* __restrict__ o_lat) {
  const int bid = blockIdx.x;
  const int xcd = bid & 7, idx = bid >> 3;
  const int b = xcd >> 1;
  const int h = idx & 15;
  const int jp = ((xcd & 1) << 1) | (idx >> 4);   // 0..3
  const int wv = threadIdx.x >> 6, lane = threadIdx.x & 63;
  const int g = lane >> 4, r = lane & 15;
  const int xm = (r & 7) << 3;

  __shared__ __attribute__((aligned(16))) u16 Ks[2][32 * 512];  // 64 KB swz K
  __shared__ __attribute__((aligned(16))) u16 Vs[2][32 * 512];  // 64 KB subtiled V
  __shared__ __attribute__((aligned(16))) u16 Kp[2][32 * 64];   // 8 KB swz kpe
  __shared__ __attribute__((aligned(16))) u16 P[128][40];       // 10 KB
  __shared__ float alphab[128];
  __shared__ float lbuf[128];

  const u16* KVg = kv_sw + (long)b * SS * KVR;
  const u16* VGg = v8g   + (long)b * SS * KVR;
  const u16* KPg = kpe_sw + (long)b * SS * ROPE;

  auto stage = [&](int bs, int t0) {
#pragma unroll
    for (int i = 0; i < 4; ++i) {
      int row = wv * 4 + i;
      gll16(KVg + (long)(t0 + row) * KVR + lane * 8, &Ks[bs][row * 512]);
      gll16(VGg + (long)t0 * KVR + i * 4096 + wv * 512 + lane * 8,
            &Vs[bs][i * 4096 + wv * 512]);
    }
    if (wv < 4)
      gll16(KPg + (long)t0 * ROPE + wv * 512 + lane * 8, &Kp[bs][wv * 512]);
  };

  for (int seg = 0; seg < 2; ++seg) {
    const int jc = seg ? (7 - jp) : jp;
    const int qa = jc * 128;
    const int nt = 4 * jc + 4;             // 32-key tiles
    const int q_row = qa + wv * 16 + r;

    const u16* Q  = q_lat + ((long)h * NTOK + (long)b * SS + q_row) * KVR;
    const u16* Qp = q_pe  + ((long)h * NTOK + (long)b * SS + q_row) * ROPE;
    bf16x8 qf[18];
#pragma unroll
    for (int c = 0; c < 16; ++c) qf[c] = *(const bf16x8*)&Q[c * 32 + g * 8];
    qf[16] = *(const bf16x8*)&Qp[g * 8];
    qf[17] = *(const bf16x8*)&Qp[32 + g * 8];

    f32x4 acc[8][4];
#pragma unroll
    for (int i = 0; i < 8; i++)
#pragma unroll
      for (int jn = 0; jn < 4; jn++) acc[i][jn] = f32x4{0.f, 0.f, 0.f, 0.f};
    float m_run = -1e30f, l_run = 0.f;

    stage(0, 0);
    __syncthreads();

    for (int tt = 0; tt < nt; ++tt) {
      const int t0 = tt << 5;
      const int bs = tt & 1;
      if (tt + 1 < nt) stage(bs ^ 1, t0 + 32);   // issue early; drained at B1

      // QK^T over 32 keys (2 row-groups of 16), 18 c-steps
      f32x4 st0 = {0.f, 0.f, 0.f, 0.f}, st1 = {0.f, 0.f, 0.f, 0.f};
#pragma unroll
      for (int c = 0; c < 16; ++c) {
        int ix = (c * 32 + g * 8) ^ xm;
        bf16x8 k0 = *(const bf16x8*)&Ks[bs][r * 512 + ix];
        bf16x8 k1 = *(const bf16x8*)&Ks[bs][(16 + r) * 512 + ix];
        st0 = MFMA16(k0, qf[c], st0, 0, 0, 0);
        st1 = MFMA16(k1, qf[c], st1, 0, 0, 0);
      }
#pragma unroll
      for (int c = 0; c < 2; ++c) {
        int ix = (c * 32 + g * 8) ^ xm;
        bf16x8 k0 = *(const bf16x8*)&Kp[bs][r * 64 + ix];
        bf16x8 k1 = *(const bf16x8*)&Kp[bs][(16 + r) * 64 + ix];
        st0 = MFMA16(k0, qf[16 + c], st0, 0, 0, 0);
        st1 = MFMA16(k1, qf[16 + c], st1, 0, 0, 0);
      }

      // softmax (lane owns q_row; keys {t0+g*4+i, t0+16+g*4+i})
      float sv[8];
      float smax = -1e30f;
#pragma unroll
      for (int i = 0; i < 4; i++) {
        int t = t0 + g * 4 + i;
        sv[i]     = (t      <= q_row) ? st0[i] : -1e30f;
        sv[4 + i] = (t + 16 <= q_row) ? st1[i] : -1e30f;
        smax = fmaxf(smax, fmaxf(sv[i], sv[4 + i]));
      }
      smax = fmaxf(smax, __shfl_xor(smax, 16));
      smax = fmaxf(smax, __shfl_xor(smax, 32));
      float m_new = fmaxf(m_run, smax);
      float alpha = __expf(m_run - m_new);
      float p[8], ps = 0.f;
#pragma unroll
      for (int i = 0; i < 8; i++) {
        p[i] = (sv[i] < -1e29f) ? 0.f : __expf(sv[i] - m_new);
        ps += p[i];
      }
      ps += __shfl_xor(ps, 16);
      ps += __shfl_xor(ps, 32);
      l_run = l_run * alpha + ps;
      m_run = m_new;

      uint2 pw0, pw1;
      pw0.x = pk2(p[0], p[1]); pw0.y = pk2(p[2], p[3]);
      pw1.x = pk2(p[4], p[5]); pw1.y = pk2(p[6], p[7]);
      *(uint2*)&P[wv * 16 + r][g * 4]      = pw0;
      *(uint2*)&P[wv * 16 + r][16 + g * 4] = pw1;
      if (g == 0) alphab[wv * 16 + r] = alpha;
      __syncthreads();   // B1: P/alpha visible; stage(t+1) drained (hidden under QK)

      // PV: all 128 rows x own 64 cols; V-fragments single b128 LDS reads
      bf16x8 vf[4];
#pragma unroll
      for (int nc = 0; nc < 4; ++nc)
        vf[nc] = *(const bf16x8*)&Vs[bs][((g << 9) + (wv << 6) + (nc << 4) + r) << 3];
#pragma unroll
      for (int mc = 0; mc < 8; ++mc) {
        bf16x8 pa = *(const bf16x8*)&P[mc * 16 + r][g * 8];
        f32x4 a4 = *(const f32x4*)&alphab[mc * 16 + g * 4];
#pragma unroll
        for (int nc = 0; nc < 4; ++nc) {
          f32x4 t = acc[mc][nc] * a4;
          acc[mc][nc] = MFMA16(pa, vf[nc], t, 0, 0, 0);
        }
      }
      __syncthreads();   // B2: PV done -> buf safe to restage; P safe to rewrite
    }

    if (g == 0) lbuf[wv * 16 + r] = l_run;
    __syncthreads();
    u16* O = o_lat + ((long)h * NTOK + (long)b * SS + qa) * KVR;
#pragma unroll
    for (int mc = 0; mc < 8; ++mc) {
      f32x4 li = *(const f32x4*)&lbuf[mc * 16 + g * 4];
#pragma unroll
      for (int e = 0; e < 4; e++) li[e] = 1.f / li[e];
#pragma unroll
      for (int nc = 0; nc < 4; ++nc) {
        int col = wv * 64 + nc * 16 + r;
#pragma unroll
        for (int e = 0; e < 4; e++)
          O[(long)(mc * 16 + g * 4 + e) * KVR + col] = f2b(acc[mc][nc][e] * li[e]);
      }
    }
    __syncthreads();                       // lbuf/LDS safe for next seg
  }
}

// ---------------- host launch ----------------
extern "C" void kernel_launch(void* const* d_in, const int* in_sizes, int n_in,
                              void* d_out, int out_size, void* d_ws, size_t ws_size,
                              hipStream_t stream) {
  (void)in_sizes; (void)n_in; (void)out_size; (void)ws_size;
  const float* x    = (const float*)d_in[0];
  const float* fc   = (const float*)d_in[2];
  const float* fs   = (const float*)d_in[3];
  const float* wqa  = (const float*)d_in[4];
  const float* qnw  = (const float*)d_in[5];
  const float* wqb  = (const float*)d_in[6];
  const float* wkva = (const float*)d_in[7];
  const float* kvnw = (const float*)d_in[8];
  const float* wkvb = (const float*)d_in[9];
  const float* wo   = (const float*)d_in[10];
  float* out = (float*)d_out;

  char* w = (char*)d_ws;
  size_t off = 0;
  auto alloc = [&](size_t bytes) {
    void* p = w + off;
    off += (bytes + 255) & ~(size_t)255;
    return p;
  };
  // ---- persistent region ----
  u16* wbkt   = (u16*)alloc((size_t)NH * KVR * NOPE * 2);
  u16* wbv    = (u16*)alloc((size_t)NH * VH * KVR * 2);
  u16* wo_b   = (u16*)alloc((size_t)DIM * DIM * 2);
  u16* qnope  = (u16*)alloc((size_t)NH * NTOK * NOPE * 2);
  u16* qpe    = (u16*)alloc((size_t)NH * NTOK * ROPE * 2);
  u16* kv_sw  = (u16*)alloc((size_t)BB * SS * KVR * 2);
  u16* v8b    = (u16*)alloc((size_t)BB * SS * KVR * 2);
  u16* kpe_sw = (u16*)alloc((size_t)BB * SS * ROPE * 2);
  u16* oflat  = (u16*)alloc((size_t)NTOK * DIM * 2);
  // ---- transient region, later overlaid by qlat/olat ----
  u16* qlat   = (u16*)(w + off);            // overlay base
  u16* olat   = qlat;                       // attention writes O in-place over Q
  u16* x_bf   = (u16*)alloc((size_t)NTOK * DIM * 2);
  u16* wqa_b  = (u16*)alloc((size_t)QR * DIM * 2);
  u16* wqb_b  = (u16*)alloc((size_t)NH * QKH * QR * 2);
  u16* wkva_b = (u16*)alloc((size_t)576 * DIM * 2);
  u16* qn     = (u16*)alloc((size_t)NTOK * QR * 2);
  float* C1   = (float*)alloc((size_t)NTOK * QR * 4);
  u16* C2b    = (u16*)alloc((size_t)NTOK * NH * QKH * 2);

  cvt_bf16<<<(NTOK * DIM) / 2048, 256, 0, stream>>>(x, x_bf, NTOK * DIM);
  cvt_bf16<<<(QR * DIM) / 2048, 256, 0, stream>>>(wqa, wqa_b, QR * DIM);
  cvt_bf16<<<(NH * QKH * QR) / 2048, 256, 0, stream>>>(wqb, wqb_b, NH * QKH * QR);
  cvt_bf16<<<(576 * DIM) / 2048, 256, 0, stream>>>(wkva, wkva_b, 576 * DIM);
  cvt_bf16<<<(DIM * DIM) / 2048, 256, 0, stream>>>(wo, wo_b, DIM * DIM);
  prep_wkvb<<<(NH * 256 * KVR) / 256, 256, 0, stream>>>(wkvb, wbkt, wbv);

  gemm_bt<false><<<dim3(QR / 128, NTOK / 128, 1), 256, 0, stream>>>(
      x_bf, wqa_b, C1, NTOK, QR, DIM, DIM, DIM, QR, 0, 0, 0, 1.f);
  rms_q_kernel<<<NTOK, 256, 0, stream>>>(C1, qnw, qn);
  gemm_bt<true><<<dim3(NH * QKH / 128, NTOK / 128, 1), 256, 0, stream>>>(
      qn, wqb_b, C2b, NTOK, NH * QKH, QR, QR, QR, NH * QKH, 0, 0, 0, 1.f);
  post_q_kernel<<<NTOK, 256, 0, stream>>>(C2b, fc, fs, qnope, qpe);
  gemm_bt<false><<<dim3(5, NTOK / 128, 1), 256, 0, stream>>>(
      x_bf, wkva_b, C1, NTOK, 576, DIM, DIM, DIM, 576, 0, 0, 0, 1.f);
  post_kv_kernel<<<NTOK, 256, 0, stream>>>(C1, kvnw, fc, fs, kv_sw, v8b, kpe_sw);
  // q_lat pre-scaled by SCALE_ (softmax scale folded into Q)
  gemm_bt<true><<<dim3(KVR / 128, NTOK / 128, NH), 256, 0, stream>>>(
      qnope, wbkt, qlat, NTOK, KVR, NOPE, NOPE, NOPE, KVR,
      (long)NTOK * NOPE, (long)KVR * NOPE, (long)NTOK * KVR, SCALE_);
  attn_kernel<<<dim3(256, 1, 1), 512, 0, stream>>>(
      qlat, qpe, kv_sw, v8b, kpe_sw, olat);
  gemm_bt<true><<<dim3(1, NTOK / 128, NH), 256, 0, stream>>>(
      olat, wbv, oflat, NTOK, VH, KVR, KVR, KVR, DIM,
      (long)NTOK * KVR, (long)VH * KVR, (long)VH, 1.f);
  gemm_bt<false><<<dim3(DIM / 128, NTOK / 128, 1), 256, 0, stream>>>(
      oflat, wo_b, out, NTOK, DIM, DIM, DIM, DIM, DIM, 0, 0, 0, 1.f);
}

// Round 9
// 462.155 us; speedup vs baseline: 1.1852x; 1.0692x over previous
//
#include <hip/hip_runtime.h>
#include <hip/hip_bf16.h>
#include <stdint.h>

#define BB 4
#define SS 1024
#define DIM 2048
#define NH 16
#define QR 1024
#define KVR 512
#define NOPE 128
#define ROPE 64
#define VH 128
#define QKH 192
#define NTOK 4096

static constexpr float SCALE_ = 0.07216878364870322f; // 192^-0.5
static constexpr float EPS_ = 1e-6f;

typedef unsigned short u16;
typedef unsigned int u32;
using f32x4  = __attribute__((ext_vector_type(4))) float;
using bf16x8 = __attribute__((ext_vector_type(8))) __bf16;

#define MFMA16 __builtin_amdgcn_mfma_f32_16x16x32_bf16

__device__ __forceinline__ u16 f2b(float f) {
  u32 u = __float_as_uint(f);
  u32 r = u + 0x7fffu + ((u >> 16) & 1u);   // RNE
  return (u16)(r >> 16);
}
__device__ __forceinline__ u32 pk2(float a, float b) {
  return (u32)f2b(a) | ((u32)f2b(b) << 16);
}
__device__ __forceinline__ float b2f(u32 hi16) {
  return __uint_as_float(hi16 << 16);
}
__device__ __forceinline__ void gll16(const u16* g, u16* l) {
  __builtin_amdgcn_global_load_lds(
      (const __attribute__((address_space(1))) void*)g,
      (__attribute__((address_space(3))) void*)l, 16, 0, 0);
}

// ---------------- f32 -> bf16 convert (8 elems/thread) ----------------
__global__ __launch_bounds__(256) void cvt_bf16(const float* __restrict__ in,
                                                u16* __restrict__ out, int n) {
  int i = (blockIdx.x * 256 + threadIdx.x) * 8;
  if (i >= n) return;
  float4 a = *(const float4*)&in[i];
  float4 b = *(const float4*)&in[i + 4];
  uint4 o;
  o.x = pk2(a.x, a.y); o.y = pk2(a.z, a.w);
  o.z = pk2(b.x, b.y); o.w = pk2(b.z, b.w);
  *(uint4*)&out[i] = o;
}

// ---------------- wkv_b split: wb_k transposed per head, wb_v straight ----------------
__global__ __launch_bounds__(256) void prep_wkvb(const float* __restrict__ w,
                                                 u16* __restrict__ wbkt,
                                                 u16* __restrict__ wbv) {
  int idx = blockIdx.x * 256 + threadIdx.x;   // over 16*256*512
  int c = idx & 511;
  int rowh = idx >> 9;
  int h = rowh >> 8;
  int dr = rowh & 255;
  float v = w[idx];
  if (dr < NOPE) wbkt[((h * KVR + c) << 7) + dr] = f2b(v);           // (NH,512,128)
  else           wbv[((h * VH + (dr - NOPE)) << 9) + c] = f2b(v);    // (NH,128,512)
}

// ---------------- RMSNorm over 1024 (q path) ----------------
__global__ __launch_bounds__(256) void rms_q_kernel(const float* __restrict__ X,
                                                    const float* __restrict__ w,
                                                    u16* __restrict__ out) {
  int r = blockIdx.x, tid = threadIdx.x;
  const float4 v = *(const float4*)&X[(long)r * QR + tid * 4];
  float ss = v.x * v.x + v.y * v.y + v.z * v.z + v.w * v.w;
  for (int m = 1; m < 64; m <<= 1) ss += __shfl_xor(ss, m);
  __shared__ float red[4];
  if ((tid & 63) == 0) red[tid >> 6] = ss;
  __syncthreads();
  float tot = red[0] + red[1] + red[2] + red[3];
  float sc = rsqrtf(tot / QR + EPS_);
  float4 wv = *(const float4*)&w[tid * 4];
  uint2 o;
  o.x = pk2(v.x * sc * wv.x, v.y * sc * wv.y);
  o.y = pk2(v.z * sc * wv.z, v.w * sc * wv.w);
  *(uint2*)&out[(long)r * QR + tid * 4] = o;
}

// ---------------- q post (bf16 input): split nope / rope(pe)*SCALE, head-major ----------------
__global__ __launch_bounds__(256) void post_q_kernel(const u16* __restrict__ C2,
                                                     const float* __restrict__ fc,
                                                     const float* __restrict__ fs,
                                                     u16* __restrict__ qn,
                                                     u16* __restrict__ qp) {
  int r = blockIdx.x, tid = threadIdx.x;
  int s = r & (SS - 1);
  const u16* row = C2 + (long)r * (NH * QKH);
  for (int j = tid; j < NH * QKH / 2; j += 256) {
    int col = j * 2;
    int h = col / QKH;
    int dd = col - h * QKH;
    u32 pair = *(const u32*)&row[col];
    if (dd < NOPE) {
      *(u32*)&qn[((long)h * NTOK + r) * NOPE + dd] = pair;   // already bf16
    } else {
      float x0 = b2f(pair & 0xffffu), x1 = b2f(pair >> 16);
      int jr = (dd - NOPE) >> 1;
      float c = fc[s * 32 + jr], sn = fs[s * 32 + jr];
      *(u32*)&qp[((long)h * NTOK + r) * ROPE + (dd - NOPE)] =
          pk2((x0 * c - x1 * sn) * SCALE_, (x0 * sn + x1 * c) * SCALE_);
    }
  }
}

// ---------------- kv post: rmsnorm(512) -> kv_sw (XOR-swizzled) + v8 (k-subtiled), rope k_pe_sw ----
__global__ __launch_bounds__(256) void post_kv_kernel(const float* __restrict__ C3,
                                                      const float* __restrict__ w,
                                                      const float* __restrict__ fc,
                                                      const float* __restrict__ fs,
                                                      u16* __restrict__ kv_sw,
                                                      u16* __restrict__ v8,
                                                      u16* __restrict__ kpe_sw) {
  int r = blockIdx.x, tid = threadIdx.x;
  int b = r >> 10, t = r & (SS - 1);
  const float* row = C3 + (long)r * 576;
  float2 v = *(const float2*)&row[tid * 2];
  float ss = v.x * v.x + v.y * v.y;
  for (int m = 1; m < 64; m <<= 1) ss += __shfl_xor(ss, m);
  __shared__ float red[4];
  if ((tid & 63) == 0) red[tid >> 6] = ss;
  __syncthreads();
  float tot = red[0] + red[1] + red[2] + red[3];
  float sc = rsqrtf(tot / KVR + EPS_);
  int c = tid * 2;
  int xm = (t & 7) << 3;
  float y0 = v.x * sc * w[c], y1 = v.y * sc * w[c + 1];
  *(u32*)&kv_sw[((long)b * SS + t) * KVR + (c ^ xm)] = pk2(y0, y1);
  long o8 = (long)b * SS * KVR + ((long)(t >> 3) * 512 + c) * 8 + (t & 7);
  v8[o8]     = f2b(y0);
  v8[o8 + 8] = f2b(y1);
  if (tid < 32) {
    float x0 = row[KVR + tid * 2], x1 = row[KVR + tid * 2 + 1];
    float cc = fc[t * 32 + tid], sn = fs[t * 32 + tid];
    *(u32*)&kpe_sw[((long)b * SS + t) * ROPE + ((tid * 2) ^ xm)] =
        pk2(x0 * cc - x1 * sn, x0 * sn + x1 * cc);
  }
}

// ---------------- GEMM: C(M,N) = A(M,K) * B(N,K)^T, bf16 in, f32/bf16 out ----------------
template <bool CBF16>
__global__ __launch_bounds__(256) void gemm_bt(const u16* __restrict__ Ag,
                                               const u16* __restrict__ Bg,
                                               void* __restrict__ Cg,
                                               int M, int N, int K,
                                               int lda, int ldb, int ldc,
                                               long sA, long sB, long sC,
                                               float oscale) {
  const u16* A = Ag + (long)blockIdx.z * sA;
  const u16* Bm = Bg + (long)blockIdx.z * sB;
  const int row0 = blockIdx.y * 128;
  const int col0 = blockIdx.x * 128;
  const int tid = threadIdx.x;
  const int wave = tid >> 6, lane = tid & 63;
  const int g = lane >> 4, r = lane & 15;
  const int wr = wave >> 1, wc = wave & 1;

  __shared__ u16 As[2][128 * 32];
  __shared__ u16 Bs[2][128 * 32];

  f32x4 acc[4][4] = {};
  const int nk = K >> 5;

  auto stage = [&](int kt, int p) {
    int k0 = kt << 5;
#pragma unroll
    for (int j = 0; j < 2; ++j) {
      int ldsoff = (j * 4096 + wave * 1024) >> 1;
      int rowi = j * 64 + wave * 16 + (lane >> 2);
      int coli = (lane & 3) << 3;
      const u16* ga = A + (long)(row0 + rowi) * lda + k0 + coli;
      gll16(ga, &As[p][ldsoff]);
      int rb = col0 + rowi; if (rb > N - 1) rb = N - 1;
      const u16* gb = Bm + (long)rb * ldb + k0 + coli;
      gll16(gb, &Bs[p][ldsoff]);
    }
  };

  stage(0, 0);
  for (int kt = 0; kt < nk; ++kt) {
    __syncthreads();
    if (kt + 1 < nk) stage(kt + 1, (kt + 1) & 1);
    const int p = kt & 1;
    bf16x8 af[4], bf[4];
#pragma unroll
    for (int i = 0; i < 4; i++) {
      af[i] = *(const bf16x8*)&As[p][(wr * 64 + i * 16 + r) * 32 + g * 8];
      bf[i] = *(const bf16x8*)&Bs[p][(wc * 64 + i * 16 + r) * 32 + g * 8];
    }
#pragma unroll
    for (int i = 0; i < 4; i++)
#pragma unroll
      for (int j = 0; j < 4; j++)
        acc[i][j] = MFMA16(af[i], bf[j], acc[i][j], 0, 0, 0);
  }

#pragma unroll
  for (int i = 0; i < 4; i++)
#pragma unroll
    for (int j = 0; j < 4; j++) {
      int rowb = row0 + wr * 64 + i * 16 + g * 4;
      int colc = col0 + wc * 64 + j * 16 + r;
      if (colc < N) {
        if constexpr (CBF16) {
          u16* C = (u16*)Cg + (long)blockIdx.z * sC;
#pragma unroll
          for (int e = 0; e < 4; e++)
            C[(long)(rowb + e) * ldc + colc] = f2b(acc[i][j][e] * oscale);
        } else {
          float* C = (float*)Cg + (long)blockIdx.z * sC;
#pragma unroll
          for (int e = 0; e < 4; e++)
            C[(long)(rowb + e) * ldc + colc] = acc[i][j][e] * oscale;
        }
      }
    }
}

// ---------------- flash attention v9: 4-wave blocks, 2 independent blocks/CU ----------------
// 512 blocks (4b x 16h x 8 chunk-pairs), 256 threads, 64 q-rows per block,
// paired chunks (j, 15-j) of 64 rows => exactly 34 tiles/block, one clean round
// at 2 blocks/CU (LDS 74KB). Single-buffer K/V/kpe: vf read to regs BEFORE B1,
// stage(t+1) after B1 (drained at B2). Cross-block TLP hides phase stalls.
__global__ __launch_bounds__(256) void attn_kernel(
    const u16* __restrict__ q_lat, const u16* __restrict__ q_pe,
    const u16* __restrict__ kv_sw, const u16* __restrict__ v8g,
    const u16* __restrict__ kpe_sw, u16* __restrict__ o_lat) {
  const int bid = blockIdx.x;
  const int xcd = bid & 7, idx = bid >> 3;
  const int b = xcd >> 1;
  const int h = idx & 15;
  const int jp = (idx >> 4) | ((xcd & 1) << 2);   // 0..7
  const int wv = threadIdx.x >> 6, lane = threadIdx.x & 63;
  const int g = lane >> 4, r = lane & 15;
  const int xm = (r & 7) << 3;

  __shared__ __attribute__((aligned(16))) u16 Ks[32 * 512];   // 32 KB swz K
  __shared__ __attribute__((aligned(16))) u16 Vs[32 * 512];   // 32 KB subtiled V
  __shared__ __attribute__((aligned(16))) u16 Kp[32 * 64];    // 4 KB swz kpe
  __shared__ __attribute__((aligned(16))) u16 P[64][40];      // 5 KB
  __shared__ float alphab[64];
  __shared__ float lbuf[64];

  const u16* KVg = kv_sw + (long)b * SS * KVR;
  const u16* VGg = v8g   + (long)b * SS * KVR;
  const u16* KPg = kpe_sw + (long)b * SS * ROPE;

  auto stage = [&](int t0) {
#pragma unroll
    for (int i = 0; i < 8; ++i) {
      int row = wv * 8 + i;
      gll16(KVg + (long)(t0 + row) * KVR + lane * 8, &Ks[row * 512]);
      gll16(VGg + (long)t0 * KVR + wv * 4096 + i * 512 + lane * 8,
            &Vs[wv * 4096 + i * 512]);
    }
    gll16(KPg + (long)t0 * ROPE + wv * 512 + lane * 8, &Kp[wv * 512]);
  };

  for (int seg = 0; seg < 2; ++seg) {
    const int j = seg ? jp : (15 - jp);    // big chunk first
    const int qa = j * 64;
    const int nt = 2 * (j + 1);            // 32-key tiles
    const int q_row = qa + wv * 16 + r;

    const u16* Q  = q_lat + ((long)h * NTOK + (long)b * SS + q_row) * KVR;
    const u16* Qp = q_pe  + ((long)h * NTOK + (long)b * SS + q_row) * ROPE;
    bf16x8 qf[18];
#pragma unroll
    for (int c = 0; c < 16; ++c) qf[c] = *(const bf16x8*)&Q[c * 32 + g * 8];
    qf[16] = *(const bf16x8*)&Qp[g * 8];
    qf[17] = *(const bf16x8*)&Qp[32 + g * 8];

    f32x4 acc[4][8];
#pragma unroll
    for (int i = 0; i < 4; i++)
#pragma unroll
      for (int jn = 0; jn < 8; jn++) acc[i][jn] = f32x4{0.f, 0.f, 0.f, 0.f};
    float m_run = -1e30f, l_run = 0.f;

    stage(0);
    __syncthreads();

    for (int tt = 0; tt < nt; ++tt) {
      const int t0 = tt << 5;

      // QK^T over 32 keys (2 row-groups of 16), 18 c-steps
      f32x4 st0 = {0.f, 0.f, 0.f, 0.f}, st1 = {0.f, 0.f, 0.f, 0.f};
#pragma unroll
      for (int c = 0; c < 16; ++c) {
        int ix = (c * 32 + g * 8) ^ xm;
        bf16x8 k0 = *(const bf16x8*)&Ks[r * 512 + ix];
        bf16x8 k1 = *(const bf16x8*)&Ks[(16 + r) * 512 + ix];
        st0 = MFMA16(k0, qf[c], st0, 0, 0, 0);
        st1 = MFMA16(k1, qf[c], st1, 0, 0, 0);
      }
#pragma unroll
      for (int c = 0; c < 2; ++c) {
        int ix = (c * 32 + g * 8) ^ xm;
        bf16x8 k0 = *(const bf16x8*)&Kp[r * 64 + ix];
        bf16x8 k1 = *(const bf16x8*)&Kp[(16 + r) * 64 + ix];
        st0 = MFMA16(k0, qf[16 + c], st0, 0, 0, 0);
        st1 = MFMA16(k1, qf[16 + c], st1, 0, 0, 0);
      }

      // V fragments for this tile -> regs (must precede B1; stage overwrites Vs)
      bf16x8 vf[8];
#pragma unroll
      for (int nc = 0; nc < 8; ++nc)
        vf[nc] = *(const bf16x8*)&Vs[((g << 9) + (wv << 7) + (nc << 4) + r) << 3];

      // softmax (lane owns q_row; keys {t0+g*4+i, t0+16+g*4+i})
      float sv[8];
      float smax = -1e30f;
#pragma unroll
      for (int i = 0; i < 4; i++) {
        int t = t0 + g * 4 + i;
        sv[i]     = (t      <= q_row) ? st0[i] : -1e30f;
        sv[4 + i] = (t + 16 <= q_row) ? st1[i] : -1e30f;
        smax = fmaxf(smax, fmaxf(sv[i], sv[4 + i]));
      }
      smax = fmaxf(smax, __shfl_xor(smax, 16));
      smax = fmaxf(smax, __shfl_xor(smax, 32));
      float m_new = fmaxf(m_run, smax);
      float alpha = __expf(m_run - m_new);
      float ps = 0.f;
#pragma unroll
      for (int i = 0; i < 8; i++) {
        sv[i] = (sv[i] < -1e29f) ? 0.f : __expf(sv[i] - m_new);
        ps += sv[i];
      }
      ps += __shfl_xor(ps, 16);
      ps += __shfl_xor(ps, 32);
      l_run = l_run * alpha + ps;
      m_run = m_new;

      uint2 pw0, pw1;
      pw0.x = pk2(sv[0], sv[1]); pw0.y = pk2(sv[2], sv[3]);
      pw1.x = pk2(sv[4], sv[5]); pw1.y = pk2(sv[6], sv[7]);
      *(uint2*)&P[wv * 16 + r][g * 4]      = pw0;
      *(uint2*)&P[wv * 16 + r][16 + g * 4] = pw1;
      if (g == 0) alphab[wv * 16 + r] = alpha;
      __syncthreads();                   // B1: P/alpha visible; all LDS reads done
      if (tt + 1 < nt) stage(t0 + 32);   // overwrite K/V/kpe; drained at B2

      // PV: all 64 rows x own 128 cols (vf in regs)
#pragma unroll
      for (int mc = 0; mc < 4; ++mc) {
        bf16x8 pa = *(const bf16x8*)&P[mc * 16 + r][g * 8];
        f32x4 a4 = *(const f32x4*)&alphab[mc * 16 + g * 4];
#pragma unroll
        for (int nc = 0; nc < 8; ++nc) {
          f32x4 t = acc[mc][nc] * a4;
          acc[mc][nc] = MFMA16(pa, vf[nc], t, 0, 0, 0);
        }
      }
      __syncthreads();                   // B2: stage drained; P safe to rewrite
    }

    if (g == 0) lbuf[wv * 16 + r] = l_run;
    __syncthreads();
    u16* O = o_lat + ((long)h * NTOK + (long)b * SS + qa) * KVR;
#pragma unroll
    for (int mc = 0; mc < 4; ++mc) {
      f32x4 li = *(const f32x4*)&lbuf[mc * 16 + g * 4];
#pragma unroll
      for (int e = 0; e < 4; e++) li[e] = 1.f / li[e];
#pragma unroll
      for (int nc = 0; nc < 8; ++nc) {
        int col = wv * 128 + nc * 16 + r;
#pragma unroll
        for (int e = 0; e < 4; e++)
          O[(long)(mc * 16 + g * 4 + e) * KVR + col] = f2b(acc[mc][nc][e] * li[e]);
      }
    }
    __syncthreads();                     // lbuf/LDS safe for next seg
  }
}

// ---------------- host launch ----------------
extern "C" void kernel_launch(void* const* d_in, const int* in_sizes, int n_in,
                              void* d_out, int out_size, void* d_ws, size_t ws_size,
                              hipStream_t stream) {
  (void)in_sizes; (void)n_in; (void)out_size; (void)ws_size;
  const float* x    = (const float*)d_in[0];
  const float* fc   = (const float*)d_in[2];
  const float* fs   = (const float*)d_in[3];
  const float* wqa  = (const float*)d_in[4];
  const float* qnw  = (const float*)d_in[5];
  const float* wqb  = (const float*)d_in[6];
  const float* wkva = (const float*)d_in[7];
  const float* kvnw = (const float*)d_in[8];
  const float* wkvb = (const float*)d_in[9];
  const float* wo   = (const float*)d_in[10];
  float* out = (float*)d_out;

  char* w = (char*)d_ws;
  size_t off = 0;
  auto alloc = [&](size_t bytes) {
    void* p = w + off;
    off += (bytes + 255) & ~(size_t)255;
    return p;
  };
  // ---- persistent region ----
  u16* wbkt   = (u16*)alloc((size_t)NH * KVR * NOPE * 2);
  u16* wbv    = (u16*)alloc((size_t)NH * VH * KVR * 2);
  u16* wo_b   = (u16*)alloc((size_t)DIM * DIM * 2);
  u16* qnope  = (u16*)alloc((size_t)NH * NTOK * NOPE * 2);
  u16* qpe    = (u16*)alloc((size_t)NH * NTOK * ROPE * 2);
  u16* kv_sw  = (u16*)alloc((size_t)BB * SS * KVR * 2);
  u16* v8b    = (u16*)alloc((size_t)BB * SS * KVR * 2);
  u16* kpe_sw = (u16*)alloc((size_t)BB * SS * ROPE * 2);
  u16* oflat  = (u16*)alloc((size_t)NTOK * DIM * 2);
  // ---- transient region, later overlaid by qlat/olat ----
  u16* qlat   = (u16*)(w + off);            // overlay base
  u16* olat   = qlat;                       // attention writes O in-place over Q
  u16* x_bf   = (u16*)alloc((size_t)NTOK * DIM * 2);
  u16* wqa_b  = (u16*)alloc((size_t)QR * DIM * 2);
  u16* wqb_b  = (u16*)alloc((size_t)NH * QKH * QR * 2);
  u16* wkva_b = (u16*)alloc((size_t)576 * DIM * 2);
  u16* qn     = (u16*)alloc((size_t)NTOK * QR * 2);
  float* C1   = (float*)alloc((size_t)NTOK * QR * 4);
  u16* C2b    = (u16*)alloc((size_t)NTOK * NH * QKH * 2);

  cvt_bf16<<<(NTOK * DIM) / 2048, 256, 0, stream>>>(x, x_bf, NTOK * DIM);
  cvt_bf16<<<(QR * DIM) / 2048, 256, 0, stream>>>(wqa, wqa_b, QR * DIM);
  cvt_bf16<<<(NH * QKH * QR) / 2048, 256, 0, stream>>>(wqb, wqb_b, NH * QKH * QR);
  cvt_bf16<<<(576 * DIM) / 2048, 256, 0, stream>>>(wkva, wkva_b, 576 * DIM);
  cvt_bf16<<<(DIM * DIM) / 2048, 256, 0, stream>>>(wo, wo_b, DIM * DIM);
  prep_wkvb<<<(NH * 256 * KVR) / 256, 256, 0, stream>>>(wkvb, wbkt, wbv);

  gemm_bt<false><<<dim3(QR / 128, NTOK / 128, 1), 256, 0, stream>>>(
      x_bf, wqa_b, C1, NTOK, QR, DIM, DIM, DIM, QR, 0, 0, 0, 1.f);
  rms_q_kernel<<<NTOK, 256, 0, stream>>>(C1, qnw, qn);
  gemm_bt<true><<<dim3(NH * QKH / 128, NTOK / 128, 1), 256, 0, stream>>>(
      qn, wqb_b, C2b, NTOK, NH * QKH, QR, QR, QR, NH * QKH, 0, 0, 0, 1.f);
  post_q_kernel<<<NTOK, 256, 0, stream>>>(C2b, fc, fs, qnope, qpe);
  gemm_bt<false><<<dim3(5, NTOK / 128, 1), 256, 0, stream>>>(
      x_bf, wkva_b, C1, NTOK, 576, DIM, DIM, DIM, 576, 0, 0, 0, 1.f);
  post_kv_kernel<<<NTOK, 256, 0, stream>>>(C1, kvnw, fc, fs, kv_sw, v8b, kpe_sw);
  // q_lat pre-scaled by SCALE_ (softmax scale folded into Q)
  gemm_bt<true><<<dim3(KVR / 128, NTOK / 128, NH), 256, 0, stream>>>(
      qnope, wbkt, qlat, NTOK, KVR, NOPE, NOPE, NOPE, KVR,
      (long)NTOK * NOPE, (long)KVR * NOPE, (long)NTOK * KVR, SCALE_);
  attn_kernel<<<dim3(512, 1, 1), 256, 0, stream>>>(
      qlat, qpe, kv_sw, v8b, kpe_sw, olat);
  gemm_bt<true><<<dim3(1, NTOK / 128, NH), 256, 0, stream>>>(
      olat, wbv, oflat, NTOK, VH, KVR, KVR, KVR, DIM,
      (long)NTOK * KVR, (long)VH * KVR, (long)VH, 1.f);
  gemm_bt<false><<<dim3(DIM / 128, NTOK / 128, 1), 256, 0, stream>>>(
      oflat, wo_b, out, NTOK, DIM, DIM, DIM, DIM, DIM, 0, 0, 0, 1.f);
}